// Round 12
// baseline (122.704 us; speedup 1.0000x reference)
//
#include <hip/hip_runtime.h>
#include <cstdint>

#define NTOK 65536
#define DIM 240
#define KP 256
#define NMETA 576
#define NGB 1024         // gating/permute blocks (64 tokens each)

typedef short bf16x8 __attribute__((ext_vector_type(8)));
typedef float f32x16 __attribute__((ext_vector_type(16)));

union U16B { uint4 u; bf16x8 v; };

__device__ __forceinline__ unsigned short f2bf(float x) {
  unsigned int u = __float_as_uint(x);
  u += 0x7fffu + ((u >> 16) & 1u);     // RNE
  return (unsigned short)(u >> 16);
}

// DPP move helpers (VALU pipe). 0xB1 = quad_perm xor1, 0x4E = quad_perm xor2,
// 0x128 = row_ror:8 (== xor8 within a 16-lane row).
template<int CTRL>
__device__ __forceinline__ float dppf(float v) {
  return __int_as_float(__builtin_amdgcn_update_dpp(0, __float_as_int(v), CTRL, 0xF, 0xF, true));
}
template<int CTRL>
__device__ __forceinline__ unsigned dppu(unsigned v) {
  return (unsigned)__builtin_amdgcn_update_dpp(0, (int)v, CTRL, 0xF, 0xF, true);
}
__device__ __forceinline__ bool pgt(unsigned a, unsigned b) {
  float fa = __uint_as_float(a & ~7u), fb = __uint_as_float(b & ~7u);
  return (fa != fb) ? (fa > fb) : ((a & 7u) < (b & 7u));
}
template<int CTRL>
__device__ __forceinline__ void top2round(unsigned& a1, unsigned& a2) {
  unsigned b1 = dppu<CTRL>(a1), b2 = dppu<CTRL>(a2);
  bool g = pgt(a1, b1);
  unsigned n1 = g ? a1 : b1;
  unsigned lo = g ? b1 : a1;
  unsigned m2 = pgt(a2, b2) ? a2 : b2;
  a2 = pgt(lo, m2) ? lo : m2;
  a1 = n1;
}

// ---------------- kernel 1: pack expert weights, granule-major: WbT[e][g32][col256][16B]
__global__ __launch_bounds__(256) void prep_w(const float* __restrict__ ew,
                                              unsigned short* __restrict__ WbT) {
  int idx = blockIdx.x * 256 + threadIdx.x;     // e(8) x n(256) x k-quad(64)
  int k0 = (idx & 63) << 2;
  int n  = (idx >> 6) & 255;
  int e  = idx >> 14;
  ushort4 v = {0, 0, 0, 0};
  if (n < DIM && k0 < DIM) {
    const float* wrow = ew + (e * DIM + n) * DIM;
    v.x = f2bf(wrow[k0]); v.y = f2bf(wrow[k0 + 1]);
    v.z = f2bf(wrow[k0 + 2]); v.w = f2bf(wrow[k0 + 3]);
  }
  *(ushort4*)&WbT[((size_t)(e * 32 + (k0 >> 3)) * 256 + n) * 8 + (k0 & 7)] = v;
}

// ---------------- kernel 2: gating (DPP reduce), 1024 blocks x 64 tokens (4/CU)
__global__ __launch_bounds__(512) void gating(const float* __restrict__ x,
                                              const float* __restrict__ gw,
                                              const float* __restrict__ gb,
                                              unsigned char* __restrict__ pairid,
                                              float2* __restrict__ wpair,
                                              int* __restrict__ hist2d) {
  __shared__ __align__(16) float gwT[8][DIM];
  __shared__ int hist[64];
  for (int i = threadIdx.x; i < 8 * DIM; i += 512) gwT[i & 7][i >> 3] = gw[i];
  if (threadIdx.x < 64) hist[threadIdx.x] = 0;
  __syncthreads();
  const int lane = threadIdx.x & 63;
  const int w = threadIdx.x >> 6;
  const bool act = lane < 60;
  float4 g[8];
#pragma unroll
  for (int e = 0; e < 8; ++e)
    g[e] = act ? *(const float4*)(&gwT[e][lane * 4]) : make_float4(0.f, 0.f, 0.f, 0.f);
  const int elane = 4 * (lane & 1) + 2 * ((lane >> 1) & 1) + ((lane >> 3) & 1);
  const float gbl = gb[elane];
  const int tbase = blockIdx.x * 64 + w * 8;
  for (int it = 0; it < 8; ++it) {
    const int t = tbase + it;
    float4 xv = act ? *(const float4*)(x + (size_t)t * DIM + lane * 4)
                    : make_float4(0.f, 0.f, 0.f, 0.f);
    float p[8];
#pragma unroll
    for (int e = 0; e < 8; ++e)
      p[e] = xv.x * g[e].x + xv.y * g[e].y + xv.z * g[e].z + xv.w * g[e].w;
    float q4[4];
#pragma unroll
    for (int i = 0; i < 4; ++i) {
      float lo = p[i] + dppf<0xB1>(p[i]);
      float hi = p[i + 4] + dppf<0xB1>(p[i + 4]);
      q4[i] = (lane & 1) ? hi : lo;
    }
    float q2[2];
#pragma unroll
    for (int i = 0; i < 2; ++i) {
      float lo = q4[i] + dppf<0x4E>(q4[i]);
      float hi = q4[i + 2] + dppf<0x4E>(q4[i + 2]);
      q2[i] = (lane & 2) ? hi : lo;
    }
    float lo = q2[0] + dppf<0x128>(q2[0]);
    float hi = q2[1] + dppf<0x128>(q2[1]);
    float s = (lane & 8) ? hi : lo;
    s += __shfl_xor(s, 4);
    s += __shfl_xor(s, 16);
    s += __shfl_xor(s, 32);
    s += gbl;
    unsigned a1 = (__float_as_uint(s) & ~7u) | (unsigned)elane;
    unsigned a2 = (0xFF800000u & ~7u) | 7u;
    top2round<0xB1>(a1, a2);
    top2round<0x4E>(a1, a2);
    top2round<0x128>(a1, a2);
    if (lane == 0) {
      const int i1 = a1 & 7, i2 = a2 & 7;
      const float l1 = __uint_as_float(a1 & ~7u), l2 = __uint_as_float(a2 & ~7u);
      const float qq = expf(l2 - l1);
      const float w1 = 1.f / (1.f + qq);
      const float w2 = qq / (1.f + qq);
      const int ea = (i1 < i2) ? i1 : i2, eb2 = (i1 < i2) ? i2 : i1;
      const float wa = (i1 < i2) ? w1 : w2, wb2 = (i1 < i2) ? w2 : w1;
      const int pp = ea * 8 + eb2;
      pairid[t] = (unsigned char)pp;
      wpair[t] = make_float2(wa, wb2);
      atomicAdd(&hist[pp], 1);                  // LDS only
    }
  }
  __syncthreads();
  if (threadIdx.x < 64) hist2d[blockIdx.x * 64 + threadIdx.x] = hist[threadIdx.x];
}

// ---------------- kernel 3: per-pair exclusive scan over 1024 block-hists (64 blocks)
__global__ __launch_bounds__(1024) void scan1_k(const int* __restrict__ hist2d,
                                                int* __restrict__ lbase2d,
                                                int* __restrict__ cnt) {
  __shared__ int s[NGB];
  const int p = blockIdx.x, tid = threadIdx.x;
  const int v = hist2d[tid * 64 + p];
  s[tid] = v;
  __syncthreads();
  for (int off = 1; off < NGB; off <<= 1) {
    int tv = (tid >= off) ? s[tid - off] : 0;
    __syncthreads();
    s[tid] += tv;
    __syncthreads();
  }
  lbase2d[tid * 64 + p] = s[tid] - v;
  if (tid == NGB - 1) cnt[p] = s[tid];
}

// ---------------- kernel 4: pair starts + tile meta (128-token tiles)
__global__ void scan2_k(const int* __restrict__ cnt, int* __restrict__ start,
                        int4* __restrict__ meta) {
  __shared__ int sc[64], sstart[64], stile[64], stot;
  const int tid = threadIdx.x;
  sc[tid] = cnt[tid];
  __syncthreads();
  if (tid == 0) {
    int a = 0, ta = 0;
    for (int p = 0; p < 64; ++p) { sstart[p] = a; stile[p] = ta; a += sc[p]; ta += (sc[p] + 127) >> 7; }
    stot = ta;
  }
  __syncthreads();
  start[tid] = sstart[tid];
  const int c = sc[tid], e0 = tid >> 3, e1 = tid & 7;
  for (int i = 0; (i << 7) < c; ++i)
    meta[stile[tid] + i] = make_int4(e0, e1, sstart[tid] + (i << 7), min(128, c - (i << 7)));
  for (int j = stot + tid; j < NMETA; j += 64)
    meta[j] = make_int4(0, 0, 0, 0);
}

// ---------------- kernel 5: permute + f32->bf16 pack (64-token blocks)
__global__ __launch_bounds__(512) void permute_k(const float* __restrict__ x,
                                                 const unsigned char* __restrict__ pairid,
                                                 const float2* __restrict__ wpair,
                                                 const int* __restrict__ start,
                                                 const int* __restrict__ lbase2d,
                                                 unsigned short* __restrict__ xbs,
                                                 float2* __restrict__ wsorted,
                                                 int* __restrict__ tokord) {
  __shared__ int lcnt[64], sp[64];
  const int b = blockIdx.x, tid = threadIdx.x;
  if (tid < 64) lcnt[tid] = 0;
  __syncthreads();
  if (tid < 64) {
    const int t = b * 64 + tid;
    const int p = pairid[t];
    const int rank = atomicAdd(&lcnt[p], 1);     // LDS only
    const int pos = start[p] + lbase2d[b * 64 + p] + rank;
    sp[tid] = pos;
    wsorted[pos] = wpair[t];
    tokord[pos] = t;
  }
  __syncthreads();
  for (int j = tid; j < 64 * 32; j += 512) {
    const int tl = j >> 5, og = j & 31;
    const size_t src = (size_t)(b * 64 + tl) * DIM + og * 8;
    ushort4 o0 = {0, 0, 0, 0}, o1 = {0, 0, 0, 0};
    if (og < 30) {
      const float4 q0 = *(const float4*)(x + src);
      const float4 q1 = *(const float4*)(x + src + 4);
      o0.x = f2bf(q0.x); o0.y = f2bf(q0.y); o0.z = f2bf(q0.z); o0.w = f2bf(q0.w);
      o1.x = f2bf(q1.x); o1.y = f2bf(q1.y); o1.z = f2bf(q1.z); o1.w = f2bf(q1.w);
    }
    unsigned short* dst = xbs + (size_t)sp[tl] * KP + og * 8;
    *(ushort4*)dst = o0;
    *(ushort4*)(dst + 4) = o1;
  }
}

// ---------------- kernel 6: pair-sparse GEMM, ZERO LDS / ZERO barriers.
// 1152 blocks x 256 thr (4 waves). Wave = 32 tokens x 128 cols x 2 experts.
// A (32 rows x 240 k) in 60 VGPRs via 15 coalesced dwordx4 (sorted xbs).
// W-frags read directly from granule-major WbT (L2/L3-resident, 512B segments).
__global__ __launch_bounds__(256, 2) void moe_gemm_pair(const unsigned short* __restrict__ xbs,
                                                        const unsigned short* __restrict__ WbT,
                                                        const float* __restrict__ ebias,
                                                        const float2* __restrict__ wsorted,
                                                        const int* __restrict__ tokord,
                                                        const int4* __restrict__ meta,
                                                        float* __restrict__ out) {
  const int4 m = meta[blockIdx.x >> 1];
  const int n = m.w;
  if (n == 0) return;
  const int ch = blockIdx.x & 1;                 // column half: cols [ch*128, ch*128+128)
  const int tid = threadIdx.x, lane = tid & 63, wid = tid >> 6;
  const int l31 = lane & 31, hi = lane >> 5;
  const int row0 = wid * 32;                     // wave's token rows

  // A fragments: frag it covers k = it*16 + hi*8 + [0..7] for row l31.
  // Per load: 32 rows x 32B contiguous segments (stride 512B) -> coalesced.
  const char* abase = (const char*)xbs + (size_t)(m.z + row0 + l31) * 512 + hi * 16;
  uint4 a[15];
#pragma unroll
  for (int it = 0; it < 15; ++it) a[it] = *(const uint4*)(abase + (size_t)it * 32);

  // W-frag base: byte = e*131072 + g*4096 + col*16; col = ch*128 + cf*32 + l31,
  // g = 2it + hi  ->  base + it*8192 + cf*512
  const char* wb0 = (const char*)WbT + (size_t)m.x * 131072 + ch * 2048 + hi * 4096 + l31 * 16;
  const char* wb1 = (const char*)WbT + (size_t)m.y * 131072 + ch * 2048 + hi * 4096 + l31 * 16;

  f32x16 acc[4][2] = {};                         // [col-frag][expert]
#pragma unroll
  for (int it = 0; it < 15; ++it) {
    U16B av; av.u = a[it];
#pragma unroll
    for (int cf = 0; cf < 4; ++cf) {
      U16B b0, b1;
      b0.u = *(const uint4*)(wb0 + (size_t)it * 8192 + cf * 512);
      b1.u = *(const uint4*)(wb1 + (size_t)it * 8192 + cf * 512);
      acc[cf][0] = __builtin_amdgcn_mfma_f32_32x32x16_bf16(av.v, b0.v, acc[cf][0], 0, 0, 0);
      acc[cf][1] = __builtin_amdgcn_mfma_f32_32x32x16_bf16(av.v, b1.v, acc[cf][1], 0, 0, 0);
    }
  }

  // epilogue: out[tok, col] = wa*(P_A + b_A[col]) + wb*(P_B + b_B[col])
#pragma unroll
  for (int cf = 0; cf < 4; ++cf) {
    const int col = ch * 128 + cf * 32 + l31;
    if (col < DIM) {
      const float be0 = ebias[m.x * DIM + col];
      const float be1 = ebias[m.y * DIM + col];
#pragma unroll
      for (int r = 0; r < 16; ++r) {
        const int rw = row0 + (r & 3) + ((r >> 2) << 3) + (hi << 2);
        if (rw < n) {
          const int t = tokord[m.z + rw];
          const float2 w2 = wsorted[m.z + rw];
          out[(size_t)t * DIM + col] =
              w2.x * (acc[cf][0][r] + be0) + w2.y * (acc[cf][1][r] + be1);
        }
      }
    }
  }
}

extern "C" void kernel_launch(void* const* d_in, const int* in_sizes, int n_in,
                              void* d_out, int out_size, void* d_ws, size_t ws_size,
                              hipStream_t stream) {
  const float* x  = (const float*)d_in[0];
  const float* gw = (const float*)d_in[1];
  const float* gb = (const float*)d_in[2];
  const float* ew = (const float*)d_in[3];
  const float* eb = (const float*)d_in[4];
  float* out = (float*)d_out;

  // workspace layout (~36.6 MB)
  char* ws = (char*)d_ws;
  unsigned short* WbT  = (unsigned short*)ws;                          // 1 MB
  unsigned short* xbs  = (unsigned short*)(ws + 1048576);              // (65536+256)*512B
  float2*         wpr  = (float2*)(ws + 34734080);                     // 512 KB
  float2*         wsr  = (float2*)(ws + 35258368);                     // (65536+256)*8B
  int*            tord = (int*)(ws + 35784704);                        // (65536+256)*4B
  unsigned char*  pid  = (unsigned char*)(ws + 36047872);              // 64 KB
  int*            h2d  = (int*)(ws + 36113408);                        // 256 KB  [1024][64]
  int*            lb2d = (int*)(ws + 36375552);                        // 256 KB  [1024][64]
  int*            cnt  = (int*)(ws + 36637696);                        // 256 B
  int*            strt = (int*)(ws + 36637952);                        // 256 B
  int4*           meta = (int4*)(ws + 36638208);                       // 9.2 KB

  prep_w<<<512, 256, 0, stream>>>(ew, WbT);
  gating<<<NGB, 512, 0, stream>>>(x, gw, gb, pid, wpr, h2d);
  scan1_k<<<64, NGB, 0, stream>>>(h2d, lb2d, cnt);
  scan2_k<<<1, 64, 0, stream>>>(cnt, strt, meta);
  permute_k<<<NGB, 512, 0, stream>>>(x, pid, wpr, strt, lb2d, xbs, wsr, tord);
  moe_gemm_pair<<<2 * NMETA, 256, 0, stream>>>(xbs, WbT, eb, wsr, tord, meta, out);
}

// Round 13
// 106.946 us; speedup vs baseline: 1.1473x; 1.1473x over previous
//
#include <hip/hip_runtime.h>
#include <cstdint>

#define NTOK 65536
#define DIM 240
#define KP 256
#define NMETA 576
#define NGB 1024         // gating blocks (64 tokens each)

typedef short bf16x8 __attribute__((ext_vector_type(8)));
typedef float f32x16 __attribute__((ext_vector_type(16)));

union U16B { uint4 u; bf16x8 v; };

__device__ __forceinline__ unsigned short f2bf(float x) {
  unsigned int u = __float_as_uint(x);
  u += 0x7fffu + ((u >> 16) & 1u);     // RNE
  return (unsigned short)(u >> 16);
}

// DPP move helpers (VALU pipe). 0xB1 = quad_perm xor1, 0x4E = quad_perm xor2,
// 0x128 = row_ror:8 (== xor8 within a 16-lane row).
template<int CTRL>
__device__ __forceinline__ float dppf(float v) {
  return __int_as_float(__builtin_amdgcn_update_dpp(0, __float_as_int(v), CTRL, 0xF, 0xF, true));
}
template<int CTRL>
__device__ __forceinline__ unsigned dppu(unsigned v) {
  return (unsigned)__builtin_amdgcn_update_dpp(0, (int)v, CTRL, 0xF, 0xF, true);
}
__device__ __forceinline__ bool pgt(unsigned a, unsigned b) {
  float fa = __uint_as_float(a & ~7u), fb = __uint_as_float(b & ~7u);
  return (fa != fb) ? (fa > fb) : ((a & 7u) < (b & 7u));
}
template<int CTRL>
__device__ __forceinline__ void top2round(unsigned& a1, unsigned& a2) {
  unsigned b1 = dppu<CTRL>(a1), b2 = dppu<CTRL>(a2);
  bool g = pgt(a1, b1);
  unsigned n1 = g ? a1 : b1;
  unsigned lo = g ? b1 : a1;
  unsigned m2 = pgt(a2, b2) ? a2 : b2;
  a2 = pgt(lo, m2) ? lo : m2;
  a1 = n1;
}

// ---------------- kernel 1: pack expert weights, granule-major: WbT[e][g32][col256][16B]
__global__ __launch_bounds__(256) void prep_w(const float* __restrict__ ew,
                                              unsigned short* __restrict__ WbT) {
  int idx = blockIdx.x * 256 + threadIdx.x;     // e(8) x n(256) x k-quad(64)
  int k0 = (idx & 63) << 2;
  int n  = (idx >> 6) & 255;
  int e  = idx >> 14;
  ushort4 v = {0, 0, 0, 0};
  if (n < DIM && k0 < DIM) {
    const float* wrow = ew + (e * DIM + n) * DIM;
    v.x = f2bf(wrow[k0]); v.y = f2bf(wrow[k0 + 1]);
    v.z = f2bf(wrow[k0 + 2]); v.w = f2bf(wrow[k0 + 3]);
  }
  *(ushort4*)&WbT[((size_t)(e * 32 + (k0 >> 3)) * 256 + n) * 8 + (k0 & 7)] = v;
}

// ---------------- kernel 2: gating (DPP reduce) + bf16 xb write, 1024 blocks x 64 tok
__global__ __launch_bounds__(512) void gating(const float* __restrict__ x,
                                              const float* __restrict__ gw,
                                              const float* __restrict__ gb,
                                              unsigned short* __restrict__ xb,
                                              unsigned char* __restrict__ pairid,
                                              float2* __restrict__ wpair,
                                              int* __restrict__ hist2d) {
  __shared__ __align__(16) float gwT[8][DIM];
  __shared__ int hist[64];
  for (int i = threadIdx.x; i < 8 * DIM; i += 512) gwT[i & 7][i >> 3] = gw[i];
  if (threadIdx.x < 64) hist[threadIdx.x] = 0;
  __syncthreads();
  const int lane = threadIdx.x & 63;
  const int w = threadIdx.x >> 6;
  const bool act = lane < 60;
  float4 g[8];
#pragma unroll
  for (int e = 0; e < 8; ++e)
    g[e] = act ? *(const float4*)(&gwT[e][lane * 4]) : make_float4(0.f, 0.f, 0.f, 0.f);
  const int elane = 4 * (lane & 1) + 2 * ((lane >> 1) & 1) + ((lane >> 3) & 1);
  const float gbl = gb[elane];
  const int tbase = blockIdx.x * 64 + w * 8;
  for (int it = 0; it < 8; ++it) {
    const int t = tbase + it;
    float4 xv = act ? *(const float4*)(x + (size_t)t * DIM + lane * 4)
                    : make_float4(0.f, 0.f, 0.f, 0.f);
    float p[8];
#pragma unroll
    for (int e = 0; e < 8; ++e)
      p[e] = xv.x * g[e].x + xv.y * g[e].y + xv.z * g[e].z + xv.w * g[e].w;
    float q4[4];
#pragma unroll
    for (int i = 0; i < 4; ++i) {
      float lo = p[i] + dppf<0xB1>(p[i]);
      float hi = p[i + 4] + dppf<0xB1>(p[i + 4]);
      q4[i] = (lane & 1) ? hi : lo;
    }
    float q2[2];
#pragma unroll
    for (int i = 0; i < 2; ++i) {
      float lo = q4[i] + dppf<0x4E>(q4[i]);
      float hi = q4[i + 2] + dppf<0x4E>(q4[i + 2]);
      q2[i] = (lane & 2) ? hi : lo;
    }
    float lo = q2[0] + dppf<0x128>(q2[0]);
    float hi = q2[1] + dppf<0x128>(q2[1]);
    float s = (lane & 8) ? hi : lo;
    s += __shfl_xor(s, 4);
    s += __shfl_xor(s, 16);
    s += __shfl_xor(s, 32);
    s += gbl;
    unsigned a1 = (__float_as_uint(s) & ~7u) | (unsigned)elane;
    unsigned a2 = (0xFF800000u & ~7u) | 7u;
    top2round<0xB1>(a1, a2);
    top2round<0x4E>(a1, a2);
    top2round<0x128>(a1, a2);
    ushort4 v = {0, 0, 0, 0};
    if (act) { v.x = f2bf(xv.x); v.y = f2bf(xv.y); v.z = f2bf(xv.z); v.w = f2bf(xv.w); }
    *(ushort4*)(xb + (size_t)t * KP + lane * 4) = v;
    if (lane == 0) {
      const int i1 = a1 & 7, i2 = a2 & 7;
      const float l1 = __uint_as_float(a1 & ~7u), l2 = __uint_as_float(a2 & ~7u);
      const float qq = expf(l2 - l1);
      const float w1 = 1.f / (1.f + qq);
      const float w2 = qq / (1.f + qq);
      const int ea = (i1 < i2) ? i1 : i2, eb2 = (i1 < i2) ? i2 : i1;
      const float wa = (i1 < i2) ? w1 : w2, wb2 = (i1 < i2) ? w2 : w1;
      const int pp = ea * 8 + eb2;
      pairid[t] = (unsigned char)pp;
      wpair[t] = make_float2(wa, wb2);
      atomicAdd(&hist[pp], 1);                  // LDS only
    }
  }
  __syncthreads();
  if (threadIdx.x < 64) hist2d[blockIdx.x * 64 + threadIdx.x] = hist[threadIdx.x];
}

// ---------------- kernel 3: per-pair exclusive scan over 1024 block-hists (64 blocks)
__global__ __launch_bounds__(1024) void scan1_k(const int* __restrict__ hist2d,
                                                int* __restrict__ lbase2d,
                                                int* __restrict__ cnt) {
  __shared__ int s[NGB];
  const int p = blockIdx.x, tid = threadIdx.x;
  const int v = hist2d[tid * 64 + p];
  s[tid] = v;
  __syncthreads();
  for (int off = 1; off < NGB; off <<= 1) {
    int tv = (tid >= off) ? s[tid - off] : 0;
    __syncthreads();
    s[tid] += tv;
    __syncthreads();
  }
  lbase2d[tid * 64 + p] = s[tid] - v;
  if (tid == NGB - 1) cnt[p] = s[tid];
}

// ---------------- kernel 4: pair starts + tile meta (128-token tiles)
__global__ void scan2_k(const int* __restrict__ cnt, int* __restrict__ start,
                        int4* __restrict__ meta) {
  __shared__ int sc[64], sstart[64], stile[64], stot;
  const int tid = threadIdx.x;
  sc[tid] = cnt[tid];
  __syncthreads();
  if (tid == 0) {
    int a = 0, ta = 0;
    for (int p = 0; p < 64; ++p) { sstart[p] = a; stile[p] = ta; a += sc[p]; ta += (sc[p] + 127) >> 7; }
    stot = ta;
  }
  __syncthreads();
  start[tid] = sstart[tid];
  const int c = sc[tid], e0 = tid >> 3, e1 = tid & 7;
  for (int i = 0; (i << 7) < c; ++i)
    meta[stile[tid] + i] = make_int4(e0, e1, sstart[tid] + (i << 7), min(128, c - (i << 7)));
  for (int j = stot + tid; j < NMETA; j += 64)
    meta[j] = make_int4(0, 0, 0, 0);
}

// ---------------- kernel 5: route only (no data copy): wsorted/tokord (1024 x 64)
__global__ __launch_bounds__(64) void route_k(const unsigned char* __restrict__ pairid,
                                              const float2* __restrict__ wpair,
                                              const int* __restrict__ start,
                                              const int* __restrict__ lbase2d,
                                              float2* __restrict__ wsorted,
                                              int* __restrict__ tokord) {
  __shared__ int lcnt[64];
  const int b = blockIdx.x, tid = threadIdx.x;
  lcnt[tid] = 0;
  __syncthreads();
  const int t = b * 64 + tid;
  const int p = pairid[t];
  const int rank = atomicAdd(&lcnt[p], 1);       // LDS only
  const int pos = start[p] + lbase2d[b * 64 + p] + rank;
  wsorted[pos] = wpair[t];
  tokord[pos] = t;
}

// ---------------- kernel 6: pair-sparse GEMM, whole-expert W staging (L paid twice per
// block, not per K-chunk). Block = 128 tok x 240 cols x 2 experts, 512 thr (8 waves =
// 4 token-quadrants x 2 col-halves; wave = 32 tok x 128 col). A in 60 VGPRs (gathered);
// W for one expert = 120KB LDS, staged linearly; 60 MFMA/wave per expert phase.
#define GLDS16(g, l)                                                        \
  __builtin_amdgcn_global_load_lds(                                         \
      (__attribute__((address_space(1))) unsigned int*)(g),                 \
      (__attribute__((address_space(3))) unsigned int*)(l), 16, 0, 0)

__global__ __launch_bounds__(512, 2) void moe_gemm_pair(const unsigned short* __restrict__ xb,
                                                        const unsigned short* __restrict__ WbT,
                                                        const float* __restrict__ ebias,
                                                        const float2* __restrict__ wsorted,
                                                        const int* __restrict__ tokord,
                                                        const int4* __restrict__ meta,
                                                        float* __restrict__ out) {
  extern __shared__ __align__(16) char smem[];
  // [0, 122880): W for current expert, layout [g 30][col 256][16B] (linear copy of WbT[e])
  int* ptok = (int*)(smem + 122880);             // 512 B
  float2* wab = (float2*)(smem + 123392);        // 1 KB

  const int4 m = meta[blockIdx.x];
  const int n = m.w;
  if (n == 0) return;
  const int tid = threadIdx.x, lane = tid & 63, wid = tid >> 6;
  const int tq = wid >> 1, chf = wid & 1;        // 4 token-quadrants x 2 col-halves
  const int l31 = lane & 31, hi = lane >> 5;

  if (tid < 128) {
    const int idx = m.z + (tid < n ? tid : n - 1);
    ptok[tid] = tokord[idx];
    wab[tid] = wsorted[idx];
  }
  __syncthreads();

  // A gather -> registers: frag it covers k = it*16 + hi*8 + [0..7] of this lane's row
  const char* ab = (const char*)xb + (size_t)ptok[tq * 32 + l31] * 512 + hi * 16;
  uint4 a[15];
#pragma unroll
  for (int it = 0; it < 15; ++it) a[it] = *(const uint4*)(ab + it * 32);

  // stage whole W of expert m.x: 15 x fully-linear GLDS16 per thread (120KB)
  const char* wsA = (const char*)WbT + (size_t)m.x * 131072 + tid * 16;
#pragma unroll
  for (int j = 0; j < 15; ++j) GLDS16(wsA + j * 8192, smem + tid * 16 + j * 8192);
  __syncthreads();                               // drain #1

  f32x16 accA[4] = {}, accB[4] = {};
  const char* wrd = smem + ((chf * 128 + l31) << 4);   // + g*4096 + cf*512

#pragma unroll
  for (int it = 0; it < 15; ++it) {
    U16B av; av.u = a[it];
    const char* wg = wrd + ((2 * it + hi) << 12);
#pragma unroll
    for (int cf = 0; cf < 4; ++cf) {
      U16B b; b.u = *(const uint4*)(wg + cf * 512);
      accA[cf] = __builtin_amdgcn_mfma_f32_32x32x16_bf16(av.v, b.v, accA[cf], 0, 0, 0);
    }
  }
  __syncthreads();                               // all waves done reading W_A

  const char* wsB = (const char*)WbT + (size_t)m.y * 131072 + tid * 16;
#pragma unroll
  for (int j = 0; j < 15; ++j) GLDS16(wsB + j * 8192, smem + tid * 16 + j * 8192);
  __syncthreads();                               // drain #2

#pragma unroll
  for (int it = 0; it < 15; ++it) {
    U16B av; av.u = a[it];
    const char* wg = wrd + ((2 * it + hi) << 12);
#pragma unroll
    for (int cf = 0; cf < 4; ++cf) {
      U16B b; b.u = *(const uint4*)(wg + cf * 512);
      accB[cf] = __builtin_amdgcn_mfma_f32_32x32x16_bf16(av.v, b.v, accB[cf], 0, 0, 0);
    }
  }

  // epilogue: out[tok, col] = wa*(P_A + b_A[col]) + wb*(P_B + b_B[col])
#pragma unroll
  for (int cf = 0; cf < 4; ++cf) {
    const int col = chf * 128 + cf * 32 + l31;
    if (col < DIM) {
      const float be0 = ebias[m.x * DIM + col];
      const float be1 = ebias[m.y * DIM + col];
#pragma unroll
      for (int r = 0; r < 16; ++r) {
        const int rw = tq * 32 + (r & 3) + ((r >> 2) << 3) + (hi << 2);
        if (rw < n) {
          const float2 w2 = wab[rw];
          out[(size_t)ptok[rw] * DIM + col] =
              w2.x * (accA[cf][r] + be0) + w2.y * (accB[cf][r] + be1);
        }
      }
    }
  }
}

extern "C" void kernel_launch(void* const* d_in, const int* in_sizes, int n_in,
                              void* d_out, int out_size, void* d_ws, size_t ws_size,
                              hipStream_t stream) {
  const float* x  = (const float*)d_in[0];
  const float* gw = (const float*)d_in[1];
  const float* gb = (const float*)d_in[2];
  const float* ew = (const float*)d_in[3];
  const float* eb = (const float*)d_in[4];
  float* out = (float*)d_out;

  // workspace layout (~36.6 MB)
  char* ws = (char*)d_ws;
  unsigned short* WbT  = (unsigned short*)ws;                          // 1 MB
  unsigned short* xb   = (unsigned short*)(ws + 1048576);              // 33 MB (unsorted bf16 [NTOK][256])
  float2*         wpr  = (float2*)(ws + 34734080);                     // 512 KB
  float2*         wsr  = (float2*)(ws + 35258368);                     // sorted weights
  int*            tord = (int*)(ws + 35784704);                        // sorted token ids
  unsigned char*  pid  = (unsigned char*)(ws + 36047872);              // 64 KB
  int*            h2d  = (int*)(ws + 36113408);                        // 256 KB  [1024][64]
  int*            lb2d = (int*)(ws + 36375552);                        // 256 KB  [1024][64]
  int*            cnt  = (int*)(ws + 36637696);                        // 256 B
  int*            strt = (int*)(ws + 36637952);                        // 256 B
  int4*           meta = (int4*)(ws + 36638208);                       // 9.2 KB

  hipFuncSetAttribute((const void*)moe_gemm_pair, hipFuncAttributeMaxDynamicSharedMemorySize, 124416);

  prep_w<<<512, 256, 0, stream>>>(ew, WbT);
  gating<<<NGB, 512, 0, stream>>>(x, gw, gb, xb, pid, wpr, h2d);
  scan1_k<<<64, NGB, 0, stream>>>(h2d, lb2d, cnt);
  scan2_k<<<1, 64, 0, stream>>>(cnt, strt, meta);
  route_k<<<NGB, 64, 0, stream>>>(pid, wpr, strt, lb2d, wsr, tord);
  moe_gemm_pair<<<NMETA, 512, 124416, stream>>>(xb, WbT, eb, wsr, tord, meta, out);
}

// Round 14
// 106.120 us; speedup vs baseline: 1.1563x; 1.0078x over previous
//
#include <hip/hip_runtime.h>
#include <cstdint>

#define NTOK 65536
#define DIM 240
#define KP 256
#define NMETA 576
#define NGB 1024         // gating blocks (64 tokens each)

typedef short bf16x8 __attribute__((ext_vector_type(8)));
typedef float f32x16 __attribute__((ext_vector_type(16)));

union U16B { uint4 u; bf16x8 v; };

__device__ __forceinline__ unsigned short f2bf(float x) {
  unsigned int u = __float_as_uint(x);
  u += 0x7fffu + ((u >> 16) & 1u);     // RNE
  return (unsigned short)(u >> 16);
}

// DPP move helpers (VALU pipe). 0xB1 = quad_perm xor1, 0x4E = quad_perm xor2,
// 0x128 = row_ror:8 (== xor8 within a 16-lane row).
template<int CTRL>
__device__ __forceinline__ float dppf(float v) {
  return __int_as_float(__builtin_amdgcn_update_dpp(0, __float_as_int(v), CTRL, 0xF, 0xF, true));
}
template<int CTRL>
__device__ __forceinline__ unsigned dppu(unsigned v) {
  return (unsigned)__builtin_amdgcn_update_dpp(0, (int)v, CTRL, 0xF, 0xF, true);
}
__device__ __forceinline__ bool pgt(unsigned a, unsigned b) {
  float fa = __uint_as_float(a & ~7u), fb = __uint_as_float(b & ~7u);
  return (fa != fb) ? (fa > fb) : ((a & 7u) < (b & 7u));
}
template<int CTRL>
__device__ __forceinline__ void top2round(unsigned& a1, unsigned& a2) {
  unsigned b1 = dppu<CTRL>(a1), b2 = dppu<CTRL>(a2);
  bool g = pgt(a1, b1);
  unsigned n1 = g ? a1 : b1;
  unsigned lo = g ? b1 : a1;
  unsigned m2 = pgt(a2, b2) ? a2 : b2;
  a2 = pgt(lo, m2) ? lo : m2;
  a1 = n1;
}

// ---------------- kernel 1: pack expert weights, granule-major: WbT[e][g32][col256][16B]
__global__ __launch_bounds__(256) void prep_w(const float* __restrict__ ew,
                                              unsigned short* __restrict__ WbT) {
  int idx = blockIdx.x * 256 + threadIdx.x;     // e(8) x n(256) x k-quad(64)
  int k0 = (idx & 63) << 2;
  int n  = (idx >> 6) & 255;
  int e  = idx >> 14;
  ushort4 v = {0, 0, 0, 0};
  if (n < DIM && k0 < DIM) {
    const float* wrow = ew + (e * DIM + n) * DIM;
    v.x = f2bf(wrow[k0]); v.y = f2bf(wrow[k0 + 1]);
    v.z = f2bf(wrow[k0 + 2]); v.w = f2bf(wrow[k0 + 3]);
  }
  *(ushort4*)&WbT[((size_t)(e * 32 + (k0 >> 3)) * 256 + n) * 8 + (k0 & 7)] = v;
}

// ---------------- kernel 2: gating (DPP reduce) + bf16 xb write, 1024 blocks x 64 tok
__global__ __launch_bounds__(512) void gating(const float* __restrict__ x,
                                              const float* __restrict__ gw,
                                              const float* __restrict__ gb,
                                              unsigned short* __restrict__ xb,
                                              unsigned char* __restrict__ pairid,
                                              float2* __restrict__ wpair,
                                              int* __restrict__ hist2d) {
  __shared__ __align__(16) float gwT[8][DIM];
  __shared__ int hist[64];
  for (int i = threadIdx.x; i < 8 * DIM; i += 512) gwT[i & 7][i >> 3] = gw[i];
  if (threadIdx.x < 64) hist[threadIdx.x] = 0;
  __syncthreads();
  const int lane = threadIdx.x & 63;
  const int w = threadIdx.x >> 6;
  const bool act = lane < 60;
  float4 g[8];
#pragma unroll
  for (int e = 0; e < 8; ++e)
    g[e] = act ? *(const float4*)(&gwT[e][lane * 4]) : make_float4(0.f, 0.f, 0.f, 0.f);
  const int elane = 4 * (lane & 1) + 2 * ((lane >> 1) & 1) + ((lane >> 3) & 1);
  const float gbl = gb[elane];
  const int tbase = blockIdx.x * 64 + w * 8;
  for (int it = 0; it < 8; ++it) {
    const int t = tbase + it;
    float4 xv = act ? *(const float4*)(x + (size_t)t * DIM + lane * 4)
                    : make_float4(0.f, 0.f, 0.f, 0.f);
    float p[8];
#pragma unroll
    for (int e = 0; e < 8; ++e)
      p[e] = xv.x * g[e].x + xv.y * g[e].y + xv.z * g[e].z + xv.w * g[e].w;
    float q4[4];
#pragma unroll
    for (int i = 0; i < 4; ++i) {
      float lo = p[i] + dppf<0xB1>(p[i]);
      float hi = p[i + 4] + dppf<0xB1>(p[i + 4]);
      q4[i] = (lane & 1) ? hi : lo;
    }
    float q2[2];
#pragma unroll
    for (int i = 0; i < 2; ++i) {
      float lo = q4[i] + dppf<0x4E>(q4[i]);
      float hi = q4[i + 2] + dppf<0x4E>(q4[i + 2]);
      q2[i] = (lane & 2) ? hi : lo;
    }
    float lo = q2[0] + dppf<0x128>(q2[0]);
    float hi = q2[1] + dppf<0x128>(q2[1]);
    float s = (lane & 8) ? hi : lo;
    s += __shfl_xor(s, 4);
    s += __shfl_xor(s, 16);
    s += __shfl_xor(s, 32);
    s += gbl;
    unsigned a1 = (__float_as_uint(s) & ~7u) | (unsigned)elane;
    unsigned a2 = (0xFF800000u & ~7u) | 7u;
    top2round<0xB1>(a1, a2);
    top2round<0x4E>(a1, a2);
    top2round<0x128>(a1, a2);
    ushort4 v = {0, 0, 0, 0};
    if (act) { v.x = f2bf(xv.x); v.y = f2bf(xv.y); v.z = f2bf(xv.z); v.w = f2bf(xv.w); }
    *(ushort4*)(xb + (size_t)t * KP + lane * 4) = v;
    if (lane == 0) {
      const int i1 = a1 & 7, i2 = a2 & 7;
      const float l1 = __uint_as_float(a1 & ~7u), l2 = __uint_as_float(a2 & ~7u);
      const float qq = expf(l2 - l1);
      const float w1 = 1.f / (1.f + qq);
      const float w2 = qq / (1.f + qq);
      const int ea = (i1 < i2) ? i1 : i2, eb2 = (i1 < i2) ? i2 : i1;
      const float wa = (i1 < i2) ? w1 : w2, wb2 = (i1 < i2) ? w2 : w1;
      const int pp = ea * 8 + eb2;
      pairid[t] = (unsigned char)pp;
      wpair[t] = make_float2(wa, wb2);
      atomicAdd(&hist[pp], 1);                  // LDS only
    }
  }
  __syncthreads();
  if (threadIdx.x < 64) hist2d[blockIdx.x * 64 + threadIdx.x] = hist[threadIdx.x];
}

// ---------------- kernel 3: per-pair exclusive scan over 1024 block-hists (64 blocks)
__global__ __launch_bounds__(1024) void scan1_k(const int* __restrict__ hist2d,
                                                int* __restrict__ lbase2d,
                                                int* __restrict__ cnt) {
  __shared__ int s[NGB];
  const int p = blockIdx.x, tid = threadIdx.x;
  const int v = hist2d[tid * 64 + p];
  s[tid] = v;
  __syncthreads();
  for (int off = 1; off < NGB; off <<= 1) {
    int tv = (tid >= off) ? s[tid - off] : 0;
    __syncthreads();
    s[tid] += tv;
    __syncthreads();
  }
  lbase2d[tid * 64 + p] = s[tid] - v;
  if (tid == NGB - 1) cnt[p] = s[tid];
}

// ---------------- kernel 4: pair starts + tile meta (128-token tiles)
__global__ void scan2_k(const int* __restrict__ cnt, int* __restrict__ start,
                        int4* __restrict__ meta) {
  __shared__ int sc[64], sstart[64], stile[64], stot;
  const int tid = threadIdx.x;
  sc[tid] = cnt[tid];
  __syncthreads();
  if (tid == 0) {
    int a = 0, ta = 0;
    for (int p = 0; p < 64; ++p) { sstart[p] = a; stile[p] = ta; a += sc[p]; ta += (sc[p] + 127) >> 7; }
    stot = ta;
  }
  __syncthreads();
  start[tid] = sstart[tid];
  const int c = sc[tid], e0 = tid >> 3, e1 = tid & 7;
  for (int i = 0; (i << 7) < c; ++i)
    meta[stile[tid] + i] = make_int4(e0, e1, sstart[tid] + (i << 7), min(128, c - (i << 7)));
  for (int j = stot + tid; j < NMETA; j += 64)
    meta[j] = make_int4(0, 0, 0, 0);
}

// ---------------- kernel 5: route only (no data copy): wsorted/tokord (1024 x 64)
__global__ __launch_bounds__(64) void route_k(const unsigned char* __restrict__ pairid,
                                              const float2* __restrict__ wpair,
                                              const int* __restrict__ start,
                                              const int* __restrict__ lbase2d,
                                              float2* __restrict__ wsorted,
                                              int* __restrict__ tokord) {
  __shared__ int lcnt[64];
  const int b = blockIdx.x, tid = threadIdx.x;
  lcnt[tid] = 0;
  __syncthreads();
  const int t = b * 64 + tid;
  const int p = pairid[t];
  const int rank = atomicAdd(&lcnt[p], 1);       // LDS only
  const int pos = start[p] + lbase2d[b * 64 + p] + rank;
  wsorted[pos] = wpair[t];
  tokord[pos] = t;
}

// ---------------- kernel 6: pair-sparse GEMM, whole-expert W phases, REGISTER-STAGED
// W copy (global->VGPR->ds_write: allocates L1/L2, unlike global_load_lds).
// Block = 128 tok x 240 cols x 2 experts, 512 thr (8 waves = 4 tok-quadrants x
// 2 col-halves; wave = 32 tok x 128 col). A in 60 VGPRs (gathered once).
__global__ __launch_bounds__(512, 2) void moe_gemm_pair(const unsigned short* __restrict__ xb,
                                                        const unsigned short* __restrict__ WbT,
                                                        const float* __restrict__ ebias,
                                                        const float2* __restrict__ wsorted,
                                                        const int* __restrict__ tokord,
                                                        const int4* __restrict__ meta,
                                                        float* __restrict__ out) {
  extern __shared__ __align__(16) char smem[];
  // [0, 122880): W for current expert, layout [g 30][col 256][16B]
  int* ptok = (int*)(smem + 122880);             // 512 B
  float2* wab = (float2*)(smem + 123392);        // 1 KB

  const int4 m = meta[blockIdx.x];
  const int n = m.w;
  if (n == 0) return;
  const int tid = threadIdx.x, lane = tid & 63, wid = tid >> 6;
  const int tq = wid >> 1, chf = wid & 1;        // 4 token-quadrants x 2 col-halves
  const int l31 = lane & 31, hi = lane >> 5;

  if (tid < 128) {
    const int idx = m.z + (tid < n ? tid : n - 1);
    ptok[tid] = tokord[idx];
    wab[tid] = wsorted[idx];
  }
  __syncthreads();

  // A gather -> registers: frag it covers k = it*16 + hi*8 + [0..7] of this lane's row
  const char* ab = (const char*)xb + (size_t)ptok[tq * 32 + l31] * 512 + hi * 16;
  uint4 a[15];
#pragma unroll
  for (int it = 0; it < 15; ++it) a[it] = *(const uint4*)(ab + it * 32);

  // ---- stage whole W of expert m.x via registers (2 batches: 8 + 7) ----
  const char* wsA = (const char*)WbT + (size_t)m.x * 131072 + tid * 16;
  {
    uint4 t0[8];
#pragma unroll
    for (int j = 0; j < 8; ++j) t0[j] = *(const uint4*)(wsA + (size_t)j * 8192);
#pragma unroll
    for (int j = 0; j < 8; ++j) *(uint4*)(smem + tid * 16 + j * 8192) = t0[j];
    uint4 t1[7];
#pragma unroll
    for (int j = 0; j < 7; ++j) t1[j] = *(const uint4*)(wsA + (size_t)(8 + j) * 8192);
#pragma unroll
    for (int j = 0; j < 7; ++j) *(uint4*)(smem + tid * 16 + (8 + j) * 8192) = t1[j];
  }
  __syncthreads();                               // W_A visible

  f32x16 accA[4] = {}, accB[4] = {};
  const char* wrd = smem + ((chf * 128 + l31) << 4);   // + g*4096 + cf*512

#pragma unroll
  for (int it = 0; it < 15; ++it) {
    U16B av; av.u = a[it];
    const char* wg = wrd + ((2 * it + hi) << 12);
#pragma unroll
    for (int cf = 0; cf < 4; ++cf) {
      U16B b; b.u = *(const uint4*)(wg + cf * 512);
      accA[cf] = __builtin_amdgcn_mfma_f32_32x32x16_bf16(av.v, b.v, accA[cf], 0, 0, 0);
    }
  }
  __syncthreads();                               // all waves done reading W_A

  // ---- stage whole W of expert m.y via registers ----
  const char* wsB = (const char*)WbT + (size_t)m.y * 131072 + tid * 16;
  {
    uint4 t0[8];
#pragma unroll
    for (int j = 0; j < 8; ++j) t0[j] = *(const uint4*)(wsB + (size_t)j * 8192);
#pragma unroll
    for (int j = 0; j < 8; ++j) *(uint4*)(smem + tid * 16 + j * 8192) = t0[j];
    uint4 t1[7];
#pragma unroll
    for (int j = 0; j < 7; ++j) t1[j] = *(const uint4*)(wsB + (size_t)(8 + j) * 8192);
#pragma unroll
    for (int j = 0; j < 7; ++j) *(uint4*)(smem + tid * 16 + (8 + j) * 8192) = t1[j];
  }
  __syncthreads();                               // W_B visible

#pragma unroll
  for (int it = 0; it < 15; ++it) {
    U16B av; av.u = a[it];
    const char* wg = wrd + ((2 * it + hi) << 12);
#pragma unroll
    for (int cf = 0; cf < 4; ++cf) {
      U16B b; b.u = *(const uint4*)(wg + cf * 512);
      accB[cf] = __builtin_amdgcn_mfma_f32_32x32x16_bf16(av.v, b.v, accB[cf], 0, 0, 0);
    }
  }

  // epilogue: out[tok, col] = wa*(P_A + b_A[col]) + wb*(P_B + b_B[col])
#pragma unroll
  for (int cf = 0; cf < 4; ++cf) {
    const int col = chf * 128 + cf * 32 + l31;
    if (col < DIM) {
      const float be0 = ebias[m.x * DIM + col];
      const float be1 = ebias[m.y * DIM + col];
#pragma unroll
      for (int r = 0; r < 16; ++r) {
        const int rw = tq * 32 + (r & 3) + ((r >> 2) << 3) + (hi << 2);
        if (rw < n) {
          const float2 w2 = wab[rw];
          out[(size_t)ptok[rw] * DIM + col] =
              w2.x * (accA[cf][r] + be0) + w2.y * (accB[cf][r] + be1);
        }
      }
    }
  }
}

extern "C" void kernel_launch(void* const* d_in, const int* in_sizes, int n_in,
                              void* d_out, int out_size, void* d_ws, size_t ws_size,
                              hipStream_t stream) {
  const float* x  = (const float*)d_in[0];
  const float* gw = (const float*)d_in[1];
  const float* gb = (const float*)d_in[2];
  const float* ew = (const float*)d_in[3];
  const float* eb = (const float*)d_in[4];
  float* out = (float*)d_out;

  // workspace layout (~36.6 MB)
  char* ws = (char*)d_ws;
  unsigned short* WbT  = (unsigned short*)ws;                          // 1 MB
  unsigned short* xb   = (unsigned short*)(ws + 1048576);              // 33 MB (unsorted bf16 [NTOK][256])
  float2*         wpr  = (float2*)(ws + 34734080);                     // 512 KB
  float2*         wsr  = (float2*)(ws + 35258368);                     // sorted weights
  int*            tord = (int*)(ws + 35784704);                        // sorted token ids
  unsigned char*  pid  = (unsigned char*)(ws + 36047872);              // 64 KB
  int*            h2d  = (int*)(ws + 36113408);                        // 256 KB  [1024][64]
  int*            lb2d = (int*)(ws + 36375552);                        // 256 KB  [1024][64]
  int*            cnt  = (int*)(ws + 36637696);                        // 256 B
  int*            strt = (int*)(ws + 36637952);                        // 256 B
  int4*           meta = (int4*)(ws + 36638208);                       // 9.2 KB

  hipFuncSetAttribute((const void*)moe_gemm_pair, hipFuncAttributeMaxDynamicSharedMemorySize, 124416);

  prep_w<<<512, 256, 0, stream>>>(ew, WbT);
  gating<<<NGB, 512, 0, stream>>>(x, gw, gb, xb, pid, wpr, h2d);
  scan1_k<<<64, NGB, 0, stream>>>(h2d, lb2d, cnt);
  scan2_k<<<1, 64, 0, stream>>>(cnt, strt, meta);
  route_k<<<NGB, 64, 0, stream>>>(pid, wpr, strt, lb2d, wsr, tord);
  moe_gemm_pair<<<NMETA, 512, 124416, stream>>>(xb, WbT, eb, wsr, tord, meta, out);
}

// Round 15
// 102.957 us; speedup vs baseline: 1.1918x; 1.0307x over previous
//
#include <hip/hip_runtime.h>
#include <cstdint>

#define NTOK 65536
#define DIM 240
#define KP 256
#define NMETA 576
#define NGB 1024         // gating blocks (64 tokens each)

typedef short bf16x8 __attribute__((ext_vector_type(8)));
typedef float f32x16 __attribute__((ext_vector_type(16)));

union U16B { uint4 u; bf16x8 v; };

__device__ __forceinline__ unsigned short f2bf(float x) {
  unsigned int u = __float_as_uint(x);
  u += 0x7fffu + ((u >> 16) & 1u);     // RNE
  return (unsigned short)(u >> 16);
}

// DPP move helpers (VALU pipe). 0xB1 = quad_perm xor1, 0x4E = quad_perm xor2,
// 0x128 = row_ror:8 (== xor8 within a 16-lane row).
template<int CTRL>
__device__ __forceinline__ float dppf(float v) {
  return __int_as_float(__builtin_amdgcn_update_dpp(0, __float_as_int(v), CTRL, 0xF, 0xF, true));
}
template<int CTRL>
__device__ __forceinline__ unsigned dppu(unsigned v) {
  return (unsigned)__builtin_amdgcn_update_dpp(0, (int)v, CTRL, 0xF, 0xF, true);
}
__device__ __forceinline__ bool pgt(unsigned a, unsigned b) {
  float fa = __uint_as_float(a & ~7u), fb = __uint_as_float(b & ~7u);
  return (fa != fb) ? (fa > fb) : ((a & 7u) < (b & 7u));
}
template<int CTRL>
__device__ __forceinline__ void top2round(unsigned& a1, unsigned& a2) {
  unsigned b1 = dppu<CTRL>(a1), b2 = dppu<CTRL>(a2);
  bool g = pgt(a1, b1);
  unsigned n1 = g ? a1 : b1;
  unsigned lo = g ? b1 : a1;
  unsigned m2 = pgt(a2, b2) ? a2 : b2;
  a2 = pgt(lo, m2) ? lo : m2;
  a1 = n1;
}

// ---------------- kernel 1: pack expert weights, granule-major: WbT[e][g32][col256][16B]
__global__ __launch_bounds__(256) void prep_w(const float* __restrict__ ew,
                                              unsigned short* __restrict__ WbT) {
  int idx = blockIdx.x * 256 + threadIdx.x;     // e(8) x n(256) x k-quad(64)
  int k0 = (idx & 63) << 2;
  int n  = (idx >> 6) & 255;
  int e  = idx >> 14;
  ushort4 v = {0, 0, 0, 0};
  if (n < DIM && k0 < DIM) {
    const float* wrow = ew + (e * DIM + n) * DIM;
    v.x = f2bf(wrow[k0]); v.y = f2bf(wrow[k0 + 1]);
    v.z = f2bf(wrow[k0 + 2]); v.w = f2bf(wrow[k0 + 3]);
  }
  *(ushort4*)&WbT[((size_t)(e * 32 + (k0 >> 3)) * 256 + n) * 8 + (k0 & 7)] = v;
}

// ---------------- kernel 2: gating (DPP reduce) + bf16 xb write, 1024 blocks x 64 tok
__global__ __launch_bounds__(512) void gating(const float* __restrict__ x,
                                              const float* __restrict__ gw,
                                              const float* __restrict__ gb,
                                              unsigned short* __restrict__ xb,
                                              unsigned char* __restrict__ pairid,
                                              float2* __restrict__ wpair,
                                              int* __restrict__ hist2d) {
  __shared__ __align__(16) float gwT[8][DIM];
  __shared__ int hist[64];
  for (int i = threadIdx.x; i < 8 * DIM; i += 512) gwT[i & 7][i >> 3] = gw[i];
  if (threadIdx.x < 64) hist[threadIdx.x] = 0;
  __syncthreads();
  const int lane = threadIdx.x & 63;
  const int w = threadIdx.x >> 6;
  const bool act = lane < 60;
  float4 g[8];
#pragma unroll
  for (int e = 0; e < 8; ++e)
    g[e] = act ? *(const float4*)(&gwT[e][lane * 4]) : make_float4(0.f, 0.f, 0.f, 0.f);
  const int elane = 4 * (lane & 1) + 2 * ((lane >> 1) & 1) + ((lane >> 3) & 1);
  const float gbl = gb[elane];
  const int tbase = blockIdx.x * 64 + w * 8;
  for (int it = 0; it < 8; ++it) {
    const int t = tbase + it;
    float4 xv = act ? *(const float4*)(x + (size_t)t * DIM + lane * 4)
                    : make_float4(0.f, 0.f, 0.f, 0.f);
    float p[8];
#pragma unroll
    for (int e = 0; e < 8; ++e)
      p[e] = xv.x * g[e].x + xv.y * g[e].y + xv.z * g[e].z + xv.w * g[e].w;
    float q4[4];
#pragma unroll
    for (int i = 0; i < 4; ++i) {
      float lo = p[i] + dppf<0xB1>(p[i]);
      float hi = p[i + 4] + dppf<0xB1>(p[i + 4]);
      q4[i] = (lane & 1) ? hi : lo;
    }
    float q2[2];
#pragma unroll
    for (int i = 0; i < 2; ++i) {
      float lo = q4[i] + dppf<0x4E>(q4[i]);
      float hi = q4[i + 2] + dppf<0x4E>(q4[i + 2]);
      q2[i] = (lane & 2) ? hi : lo;
    }
    float lo = q2[0] + dppf<0x128>(q2[0]);
    float hi = q2[1] + dppf<0x128>(q2[1]);
    float s = (lane & 8) ? hi : lo;
    s += __shfl_xor(s, 4);
    s += __shfl_xor(s, 16);
    s += __shfl_xor(s, 32);
    s += gbl;
    unsigned a1 = (__float_as_uint(s) & ~7u) | (unsigned)elane;
    unsigned a2 = (0xFF800000u & ~7u) | 7u;
    top2round<0xB1>(a1, a2);
    top2round<0x4E>(a1, a2);
    top2round<0x128>(a1, a2);
    ushort4 v = {0, 0, 0, 0};
    if (act) { v.x = f2bf(xv.x); v.y = f2bf(xv.y); v.z = f2bf(xv.z); v.w = f2bf(xv.w); }
    *(ushort4*)(xb + (size_t)t * KP + lane * 4) = v;
    if (lane == 0) {
      const int i1 = a1 & 7, i2 = a2 & 7;
      const float l1 = __uint_as_float(a1 & ~7u), l2 = __uint_as_float(a2 & ~7u);
      const float qq = expf(l2 - l1);
      const float w1 = 1.f / (1.f + qq);
      const float w2 = qq / (1.f + qq);
      const int ea = (i1 < i2) ? i1 : i2, eb2 = (i1 < i2) ? i2 : i1;
      const float wa = (i1 < i2) ? w1 : w2, wb2 = (i1 < i2) ? w2 : w1;
      const int pp = ea * 8 + eb2;
      pairid[t] = (unsigned char)pp;
      wpair[t] = make_float2(wa, wb2);
      atomicAdd(&hist[pp], 1);                  // LDS only
    }
  }
  __syncthreads();
  if (threadIdx.x < 64) hist2d[blockIdx.x * 64 + threadIdx.x] = hist[threadIdx.x];
}

// ---------------- kernel 3: per-pair exclusive scan over 1024 block-hists (64 blocks)
__global__ __launch_bounds__(1024) void scan1_k(const int* __restrict__ hist2d,
                                                int* __restrict__ lbase2d,
                                                int* __restrict__ cnt) {
  __shared__ int s[NGB];
  const int p = blockIdx.x, tid = threadIdx.x;
  const int v = hist2d[tid * 64 + p];
  s[tid] = v;
  __syncthreads();
  for (int off = 1; off < NGB; off <<= 1) {
    int tv = (tid >= off) ? s[tid - off] : 0;
    __syncthreads();
    s[tid] += tv;
    __syncthreads();
  }
  lbase2d[tid * 64 + p] = s[tid] - v;
  if (tid == NGB - 1) cnt[p] = s[tid];
}

// ---------------- kernel 4: pair starts + tile meta (128-token tiles)
__global__ void scan2_k(const int* __restrict__ cnt, int* __restrict__ start,
                        int4* __restrict__ meta) {
  __shared__ int sc[64], sstart[64], stile[64], stot;
  const int tid = threadIdx.x;
  sc[tid] = cnt[tid];
  __syncthreads();
  if (tid == 0) {
    int a = 0, ta = 0;
    for (int p = 0; p < 64; ++p) { sstart[p] = a; stile[p] = ta; a += sc[p]; ta += (sc[p] + 127) >> 7; }
    stot = ta;
  }
  __syncthreads();
  start[tid] = sstart[tid];
  const int c = sc[tid], e0 = tid >> 3, e1 = tid & 7;
  for (int i = 0; (i << 7) < c; ++i)
    meta[stile[tid] + i] = make_int4(e0, e1, sstart[tid] + (i << 7), min(128, c - (i << 7)));
  for (int j = stot + tid; j < NMETA; j += 64)
    meta[j] = make_int4(0, 0, 0, 0);
}

// ---------------- kernel 5: route only (no data copy): wsorted/tokord (1024 x 64)
__global__ __launch_bounds__(64) void route_k(const unsigned char* __restrict__ pairid,
                                              const float2* __restrict__ wpair,
                                              const int* __restrict__ start,
                                              const int* __restrict__ lbase2d,
                                              float2* __restrict__ wsorted,
                                              int* __restrict__ tokord) {
  __shared__ int lcnt[64];
  const int b = blockIdx.x, tid = threadIdx.x;
  lcnt[tid] = 0;
  __syncthreads();
  const int t = b * 64 + tid;
  const int p = pairid[t];
  const int rank = atomicAdd(&lcnt[p], 1);       // LDS only
  const int pos = start[p] + lbase2d[b * 64 + p] + rank;
  wsorted[pos] = wpair[t];
  tokord[pos] = t;
}

// ---------------- kernel 6: pair-sparse GEMM — A-in-LDS once, W register-streamed
// from L2-resident WbT, 2 barriers total, 2 blocks/CU x 8 waves = 16 waves/CU.
// Block = 128 tok x 128 cols (half) x both experts; 512 thr; wave = 32 tok x 64 col.
#define GLDS16(g, l)                                                        \
  __builtin_amdgcn_global_load_lds(                                         \
      (__attribute__((address_space(1))) unsigned int*)(g),                 \
      (__attribute__((address_space(3))) unsigned int*)(l), 16, 0, 0)

__global__ __launch_bounds__(512, 4) void moe_gemm_pair(const unsigned short* __restrict__ xb,
                                                        const unsigned short* __restrict__ WbT,
                                                        const float* __restrict__ ebias,
                                                        const float2* __restrict__ wsorted,
                                                        const int* __restrict__ tokord,
                                                        const int4* __restrict__ meta,
                                                        float* __restrict__ out) {
  extern __shared__ __align__(16) char smem[];
  // A: [g32][row128][16B] = 64KB (granules 30,31 are the zero-pad in xb rows)
  int* ptok = (int*)(smem + 65536);              // 512 B
  float2* wab = (float2*)(smem + 66048);         // 1 KB

  const int4 m = meta[blockIdx.x >> 1];
  const int n = m.w;
  if (n == 0) return;
  const int ch = blockIdx.x & 1;                 // column half
  const int tid = threadIdx.x, lane = tid & 63, wid = tid >> 6;
  const int tq = wid >> 1, cg = wid & 1;         // 4 token-quarters x 2 col-groups
  const int l31 = lane & 31, hi = lane >> 5;

  if (tid < 128) {
    const int idx = m.z + (tid < n ? tid : n - 1);
    ptok[tid] = tokord[idx];
    wab[tid] = wsorted[idx];
  }
  __syncthreads();

  // W frag pointers: frag(it, cf, e) at wbase_e + it*8192 + cf*512  (g = 2it+hi)
  const int colb = ch * 128 + cg * 64 + l31;
  const char* wbase0 = (const char*)WbT + (size_t)m.x * 131072 + (size_t)hi * 4096 + (size_t)colb * 16;
  const char* wbase1 = (const char*)WbT + (size_t)m.y * 131072 + (size_t)hi * 4096 + (size_t)colb * 16;

  // preload W for it=0 (overlaps the A-stage drain below)
  uint4 w0[4], w1[4];
  w0[0] = *(const uint4*)(wbase0);
  w0[1] = *(const uint4*)(wbase1);
  w0[2] = *(const uint4*)(wbase0 + 512);
  w0[3] = *(const uint4*)(wbase1 + 512);

  // A gather-stage once: 4096 slots (g = i>>7, row = i&127), linear LDS dest
#pragma unroll
  for (int j = 0; j < 8; ++j) {
    const int i = tid + 512 * j;
    GLDS16((const char*)xb + (size_t)ptok[i & 127] * 512 + (i >> 7) * 16, smem + i * 16);
  }
  __syncthreads();                               // the only other barrier

  f32x16 accA[2] = {}, accB[2] = {};
  const char* apt = smem + (size_t)hi * 2048 + (size_t)(tq * 32 + l31) * 16;  // + it*4096

#pragma unroll
  for (int it = 0; it < 16; ++it) {              // K = 256 (g 30,31 are zeros)
    if (it < 15) {                               // prefetch next W frags (dbuf)
      const size_t o = (size_t)(it + 1) * 8192;
      uint4* nxt = (it & 1) ? w0 : w1;           // constant after unroll
      nxt[0] = *(const uint4*)(wbase0 + o);
      nxt[1] = *(const uint4*)(wbase1 + o);
      nxt[2] = *(const uint4*)(wbase0 + o + 512);
      nxt[3] = *(const uint4*)(wbase1 + o + 512);
    }
    const uint4* cur = (it & 1) ? w1 : w0;
    U16B a; a.u = *(const uint4*)(apt + (size_t)it * 4096);
    U16B b0, b1, b2, b3;
    b0.u = cur[0]; b1.u = cur[1]; b2.u = cur[2]; b3.u = cur[3];
    accA[0] = __builtin_amdgcn_mfma_f32_32x32x16_bf16(a.v, b0.v, accA[0], 0, 0, 0);
    accB[0] = __builtin_amdgcn_mfma_f32_32x32x16_bf16(a.v, b1.v, accB[0], 0, 0, 0);
    accA[1] = __builtin_amdgcn_mfma_f32_32x32x16_bf16(a.v, b2.v, accA[1], 0, 0, 0);
    accB[1] = __builtin_amdgcn_mfma_f32_32x32x16_bf16(a.v, b3.v, accB[1], 0, 0, 0);
  }

  // epilogue: out[tok, col] = wa*(P_A + b_A[col]) + wb*(P_B + b_B[col])
#pragma unroll
  for (int cf = 0; cf < 2; ++cf) {
    const int col = ch * 128 + cg * 64 + cf * 32 + l31;
    if (col < DIM) {
      const float be0 = ebias[m.x * DIM + col];
      const float be1 = ebias[m.y * DIM + col];
#pragma unroll
      for (int r = 0; r < 16; ++r) {
        const int rw = tq * 32 + (r & 3) + ((r >> 2) << 3) + (hi << 2);
        if (rw < n) {
          const float2 w2 = wab[rw];
          out[(size_t)ptok[rw] * DIM + col] =
              w2.x * (accA[cf][r] + be0) + w2.y * (accB[cf][r] + be1);
        }
      }
    }
  }
}

extern "C" void kernel_launch(void* const* d_in, const int* in_sizes, int n_in,
                              void* d_out, int out_size, void* d_ws, size_t ws_size,
                              hipStream_t stream) {
  const float* x  = (const float*)d_in[0];
  const float* gw = (const float*)d_in[1];
  const float* gb = (const float*)d_in[2];
  const float* ew = (const float*)d_in[3];
  const float* eb = (const float*)d_in[4];
  float* out = (float*)d_out;

  // workspace layout (~36.6 MB)
  char* ws = (char*)d_ws;
  unsigned short* WbT  = (unsigned short*)ws;                          // 1 MB
  unsigned short* xb   = (unsigned short*)(ws + 1048576);              // 33 MB (unsorted bf16 [NTOK][256])
  float2*         wpr  = (float2*)(ws + 34734080);                     // 512 KB
  float2*         wsr  = (float2*)(ws + 35258368);                     // sorted weights
  int*            tord = (int*)(ws + 35784704);                        // sorted token ids
  unsigned char*  pid  = (unsigned char*)(ws + 36047872);              // 64 KB
  int*            h2d  = (int*)(ws + 36113408);                        // 256 KB  [1024][64]
  int*            lb2d = (int*)(ws + 36375552);                        // 256 KB  [1024][64]
  int*            cnt  = (int*)(ws + 36637696);                        // 256 B
  int*            strt = (int*)(ws + 36637952);                        // 256 B
  int4*           meta = (int4*)(ws + 36638208);                       // 9.2 KB

  hipFuncSetAttribute((const void*)moe_gemm_pair, hipFuncAttributeMaxDynamicSharedMemorySize, 67072);

  prep_w<<<512, 256, 0, stream>>>(ew, WbT);
  gating<<<NGB, 512, 0, stream>>>(x, gw, gb, xb, pid, wpr, h2d);
  scan1_k<<<64, NGB, 0, stream>>>(h2d, lb2d, cnt);
  scan2_k<<<1, 64, 0, stream>>>(cnt, strt, meta);
  route_k<<<NGB, 64, 0, stream>>>(pid, wpr, strt, lb2d, wsr, tord);
  moe_gemm_pair<<<2 * NMETA, 512, 67072, stream>>>(xb, WbT, eb, wsr, tord, meta, out);
}

// Round 17
// 93.790 us; speedup vs baseline: 1.3083x; 1.0977x over previous
//
#include <hip/hip_runtime.h>
#include <cstdint>

#define NTOK 65536
#define DIM 240
#define KP 256
#define NMETA 576
#define NGB 1024         // gating blocks (64 tokens each)

typedef short bf16x8 __attribute__((ext_vector_type(8)));
typedef float f32x16 __attribute__((ext_vector_type(16)));

union U16B { uint4 u; bf16x8 v; };

__device__ __forceinline__ unsigned short f2bf(float x) {
  unsigned int u = __float_as_uint(x);
  u += 0x7fffu + ((u >> 16) & 1u);     // RNE
  return (unsigned short)(u >> 16);
}

// DPP move helpers (VALU pipe). 0xB1 = quad_perm xor1, 0x4E = quad_perm xor2,
// 0x128 = row_ror:8 (== xor8 within a 16-lane row).
template<int CTRL>
__device__ __forceinline__ float dppf(float v) {
  return __int_as_float(__builtin_amdgcn_update_dpp(0, __float_as_int(v), CTRL, 0xF, 0xF, true));
}
template<int CTRL>
__device__ __forceinline__ unsigned dppu(unsigned v) {
  return (unsigned)__builtin_amdgcn_update_dpp(0, (int)v, CTRL, 0xF, 0xF, true);
}
__device__ __forceinline__ bool pgt(unsigned a, unsigned b) {
  float fa = __uint_as_float(a & ~7u), fb = __uint_as_float(b & ~7u);
  return (fa != fb) ? (fa > fb) : ((a & 7u) < (b & 7u));
}
template<int CTRL>
__device__ __forceinline__ void top2round(unsigned& a1, unsigned& a2) {
  unsigned b1 = dppu<CTRL>(a1), b2 = dppu<CTRL>(a2);
  bool g = pgt(a1, b1);
  unsigned n1 = g ? a1 : b1;
  unsigned lo = g ? b1 : a1;
  unsigned m2 = pgt(a2, b2) ? a2 : b2;
  a2 = pgt(lo, m2) ? lo : m2;
  a1 = n1;
}

// ---------------- kernel 1: gating (DPP reduce) + bf16 xb write, 1024 blocks x 64 tok.
// Blocks 0..255 additionally pack expert weights granule-major:
// WbT[e][g32][col256][16B] (fused former prep_w).
__global__ __launch_bounds__(512) void gating(const float* __restrict__ x,
                                              const float* __restrict__ gw,
                                              const float* __restrict__ gb,
                                              const float* __restrict__ ew,
                                              unsigned short* __restrict__ WbT,
                                              unsigned short* __restrict__ xb,
                                              unsigned char* __restrict__ pairid,
                                              float2* __restrict__ wpair,
                                              int* __restrict__ hist2d) {
  __shared__ __align__(16) float gwT[8][DIM];
  __shared__ int hist[64];
  // fused prep_w: gid enumerates e(8) x n(256) x k-quad(64) = 131072 slots
  {
    const int gid = blockIdx.x * 512 + threadIdx.x;
    if (gid < 131072) {
      const int k0 = (gid & 63) << 2;
      const int nn = (gid >> 6) & 255;
      const int e = gid >> 14;
      ushort4 v = {0, 0, 0, 0};
      if (nn < DIM && k0 < DIM) {
        const float* wrow = ew + (e * DIM + nn) * DIM;
        v.x = f2bf(wrow[k0]); v.y = f2bf(wrow[k0 + 1]);
        v.z = f2bf(wrow[k0 + 2]); v.w = f2bf(wrow[k0 + 3]);
      }
      *(ushort4*)&WbT[((size_t)(e * 32 + (k0 >> 3)) * 256 + nn) * 8 + (k0 & 7)] = v;
    }
  }
  for (int i = threadIdx.x; i < 8 * DIM; i += 512) gwT[i & 7][i >> 3] = gw[i];
  if (threadIdx.x < 64) hist[threadIdx.x] = 0;
  __syncthreads();
  const int lane = threadIdx.x & 63;
  const int w = threadIdx.x >> 6;
  const bool act = lane < 60;
  float4 g[8];
#pragma unroll
  for (int e = 0; e < 8; ++e)
    g[e] = act ? *(const float4*)(&gwT[e][lane * 4]) : make_float4(0.f, 0.f, 0.f, 0.f);
  const int elane = 4 * (lane & 1) + 2 * ((lane >> 1) & 1) + ((lane >> 3) & 1);
  const float gbl = gb[elane];
  const int tbase = blockIdx.x * 64 + w * 8;
  for (int it = 0; it < 8; ++it) {
    const int t = tbase + it;
    float4 xv = act ? *(const float4*)(x + (size_t)t * DIM + lane * 4)
                    : make_float4(0.f, 0.f, 0.f, 0.f);
    float p[8];
#pragma unroll
    for (int e = 0; e < 8; ++e)
      p[e] = xv.x * g[e].x + xv.y * g[e].y + xv.z * g[e].z + xv.w * g[e].w;
    float q4[4];
#pragma unroll
    for (int i = 0; i < 4; ++i) {
      float lo = p[i] + dppf<0xB1>(p[i]);
      float hi = p[i + 4] + dppf<0xB1>(p[i + 4]);
      q4[i] = (lane & 1) ? hi : lo;
    }
    float q2[2];
#pragma unroll
    for (int i = 0; i < 2; ++i) {
      float lo = q4[i] + dppf<0x4E>(q4[i]);
      float hi = q4[i + 2] + dppf<0x4E>(q4[i + 2]);
      q2[i] = (lane & 2) ? hi : lo;
    }
    float lo = q2[0] + dppf<0x128>(q2[0]);
    float hi = q2[1] + dppf<0x128>(q2[1]);
    float s = (lane & 8) ? hi : lo;
    s += __shfl_xor(s, 4);
    s += __shfl_xor(s, 16);
    s += __shfl_xor(s, 32);
    s += gbl;
    unsigned a1 = (__float_as_uint(s) & ~7u) | (unsigned)elane;
    unsigned a2 = (0xFF800000u & ~7u) | 7u;
    top2round<0xB1>(a1, a2);
    top2round<0x4E>(a1, a2);
    top2round<0x128>(a1, a2);
    ushort4 v = {0, 0, 0, 0};
    if (act) { v.x = f2bf(xv.x); v.y = f2bf(xv.y); v.z = f2bf(xv.z); v.w = f2bf(xv.w); }
    *(ushort4*)(xb + (size_t)t * KP + lane * 4) = v;
    if (lane == 0) {
      const int i1 = a1 & 7, i2 = a2 & 7;
      const float l1 = __uint_as_float(a1 & ~7u), l2 = __uint_as_float(a2 & ~7u);
      const float qq = expf(l2 - l1);
      const float w1 = 1.f / (1.f + qq);
      const float w2 = qq / (1.f + qq);
      const int ea = (i1 < i2) ? i1 : i2, eb2 = (i1 < i2) ? i2 : i1;
      const float wa = (i1 < i2) ? w1 : w2, wb2 = (i1 < i2) ? w2 : w1;
      const int pp = ea * 8 + eb2;
      pairid[t] = (unsigned char)pp;
      wpair[t] = make_float2(wa, wb2);
      atomicAdd(&hist[pp], 1);                  // LDS only
    }
  }
  __syncthreads();
  if (threadIdx.x < 64) hist2d[blockIdx.x * 64 + threadIdx.x] = hist[threadIdx.x];
}

// ---------------- kernel 2: per-pair exclusive scan over 1024 block-hists (64 blocks)
__global__ __launch_bounds__(1024) void scan1_k(const int* __restrict__ hist2d,
                                                int* __restrict__ lbase2d,
                                                int* __restrict__ cnt) {
  __shared__ int s[NGB];
  const int p = blockIdx.x, tid = threadIdx.x;
  const int v = hist2d[tid * 64 + p];
  s[tid] = v;
  __syncthreads();
  for (int off = 1; off < NGB; off <<= 1) {
    int tv = (tid >= off) ? s[tid - off] : 0;
    __syncthreads();
    s[tid] += tv;
    __syncthreads();
  }
  lbase2d[tid * 64 + p] = s[tid] - v;
  if (tid == NGB - 1) cnt[p] = s[tid];
}

// ---------------- kernel 3: pair starts + tile meta (128-token tiles)
__global__ void scan2_k(const int* __restrict__ cnt, int* __restrict__ start,
                        int4* __restrict__ meta) {
  __shared__ int sc[64], sstart[64], stile[64], stot;
  const int tid = threadIdx.x;
  sc[tid] = cnt[tid];
  __syncthreads();
  if (tid == 0) {
    int a = 0, ta = 0;
    for (int p = 0; p < 64; ++p) { sstart[p] = a; stile[p] = ta; a += sc[p]; ta += (sc[p] + 127) >> 7; }
    stot = ta;
  }
  __syncthreads();
  start[tid] = sstart[tid];
  const int c = sc[tid], e0 = tid >> 3, e1 = tid & 7;
  for (int i = 0; (i << 7) < c; ++i)
    meta[stile[tid] + i] = make_int4(e0, e1, sstart[tid] + (i << 7), min(128, c - (i << 7)));
  for (int j = stot + tid; j < NMETA; j += 64)
    meta[j] = make_int4(0, 0, 0, 0);
}

// ---------------- kernel 4: route only (no data copy): wsorted/tokord (1024 x 64)
__global__ __launch_bounds__(64) void route_k(const unsigned char* __restrict__ pairid,
                                              const float2* __restrict__ wpair,
                                              const int* __restrict__ start,
                                              const int* __restrict__ lbase2d,
                                              float2* __restrict__ wsorted,
                                              int* __restrict__ tokord) {
  __shared__ int lcnt[64];
  const int b = blockIdx.x, tid = threadIdx.x;
  lcnt[tid] = 0;
  __syncthreads();
  const int t = b * 64 + tid;
  const int p = pairid[t];
  const int rank = atomicAdd(&lcnt[p], 1);       // LDS only
  const int pos = start[p] + lbase2d[b * 64 + p] + rank;
  wsorted[pos] = wpair[t];
  tokord[pos] = t;
}

// ---------------- kernel 5: pair-sparse GEMM — A-in-LDS once, W register-streamed
// from L2-resident WbT, 2 barriers total, 2 blocks/CU x 8 waves = 16 waves/CU.
// Block = 128 tok x 128 cols (half) x both experts; 512 thr; wave = 32 tok x 64 col.
// Epilogue uses NONTEMPORAL stores (out is write-once; keep L2 for xb gathers).
#define GLDS16(g, l)                                                        \
  __builtin_amdgcn_global_load_lds(                                         \
      (__attribute__((address_space(1))) unsigned int*)(g),                 \
      (__attribute__((address_space(3))) unsigned int*)(l), 16, 0, 0)

__global__ __launch_bounds__(512, 4) void moe_gemm_pair(const unsigned short* __restrict__ xb,
                                                        const unsigned short* __restrict__ WbT,
                                                        const float* __restrict__ ebias,
                                                        const float2* __restrict__ wsorted,
                                                        const int* __restrict__ tokord,
                                                        const int4* __restrict__ meta,
                                                        float* __restrict__ out) {
  extern __shared__ __align__(16) char smem[];
  // A: [g32][row128][16B] = 64KB (granules 30,31 are the zero-pad in xb rows)
  int* ptok = (int*)(smem + 65536);              // 512 B
  float2* wab = (float2*)(smem + 66048);         // 1 KB

  const int4 m = meta[blockIdx.x >> 1];
  const int n = m.w;
  if (n == 0) return;
  const int ch = blockIdx.x & 1;                 // column half
  const int tid = threadIdx.x, lane = tid & 63, wid = tid >> 6;
  const int tq = wid >> 1, cg = wid & 1;         // 4 token-quarters x 2 col-groups
  const int l31 = lane & 31, hi = lane >> 5;

  if (tid < 128) {
    const int idx = m.z + (tid < n ? tid : n - 1);
    ptok[tid] = tokord[idx];
    wab[tid] = wsorted[idx];
  }
  __syncthreads();

  // W frag pointers: frag(it, cf, e) at wbase_e + it*8192 + cf*512  (g = 2it+hi)
  const int colb = ch * 128 + cg * 64 + l31;
  const char* wbase0 = (const char*)WbT + (size_t)m.x * 131072 + (size_t)hi * 4096 + (size_t)colb * 16;
  const char* wbase1 = (const char*)WbT + (size_t)m.y * 131072 + (size_t)hi * 4096 + (size_t)colb * 16;

  // preload W for it=0 (overlaps the A-stage drain below)
  uint4 w0[4], w1[4];
  w0[0] = *(const uint4*)(wbase0);
  w0[1] = *(const uint4*)(wbase1);
  w0[2] = *(const uint4*)(wbase0 + 512);
  w0[3] = *(const uint4*)(wbase1 + 512);

  // A gather-stage once: 4096 slots (g = i>>7, row = i&127), linear LDS dest
#pragma unroll
  for (int j = 0; j < 8; ++j) {
    const int i = tid + 512 * j;
    GLDS16((const char*)xb + (size_t)ptok[i & 127] * 512 + (i >> 7) * 16, smem + i * 16);
  }
  __syncthreads();                               // the only other barrier

  f32x16 accA[2] = {}, accB[2] = {};
  const char* apt = smem + (size_t)hi * 2048 + (size_t)(tq * 32 + l31) * 16;  // + it*4096

#pragma unroll
  for (int it = 0; it < 16; ++it) {              // K = 256 (g 30,31 are zeros)
    if (it < 15) {                               // prefetch next W frags (dbuf)
      const size_t o = (size_t)(it + 1) * 8192;
      uint4* nxt = (it & 1) ? w0 : w1;           // constant after unroll
      nxt[0] = *(const uint4*)(wbase0 + o);
      nxt[1] = *(const uint4*)(wbase1 + o);
      nxt[2] = *(const uint4*)(wbase0 + o + 512);
      nxt[3] = *(const uint4*)(wbase1 + o + 512);
    }
    const uint4* cur = (it & 1) ? w1 : w0;
    U16B a; a.u = *(const uint4*)(apt + (size_t)it * 4096);
    U16B b0, b1, b2, b3;
    b0.u = cur[0]; b1.u = cur[1]; b2.u = cur[2]; b3.u = cur[3];
    accA[0] = __builtin_amdgcn_mfma_f32_32x32x16_bf16(a.v, b0.v, accA[0], 0, 0, 0);
    accB[0] = __builtin_amdgcn_mfma_f32_32x32x16_bf16(a.v, b1.v, accB[0], 0, 0, 0);
    accA[1] = __builtin_amdgcn_mfma_f32_32x32x16_bf16(a.v, b2.v, accA[1], 0, 0, 0);
    accB[1] = __builtin_amdgcn_mfma_f32_32x32x16_bf16(a.v, b3.v, accB[1], 0, 0, 0);
  }

  // epilogue: out[tok, col] = wa*(P_A + b_A[col]) + wb*(P_B + b_B[col]); nontemporal
#pragma unroll
  for (int cf = 0; cf < 2; ++cf) {
    const int col = ch * 128 + cg * 64 + cf * 32 + l31;
    if (col < DIM) {
      const float be0 = ebias[m.x * DIM + col];
      const float be1 = ebias[m.y * DIM + col];
#pragma unroll
      for (int r = 0; r < 16; ++r) {
        const int rw = tq * 32 + (r & 3) + ((r >> 2) << 3) + (hi << 2);
        if (rw < n) {
          const float2 w2 = wab[rw];
          __builtin_nontemporal_store(
              w2.x * (accA[cf][r] + be0) + w2.y * (accB[cf][r] + be1),
              &out[(size_t)ptok[rw] * DIM + col]);
        }
      }
    }
  }
}

extern "C" void kernel_launch(void* const* d_in, const int* in_sizes, int n_in,
                              void* d_out, int out_size, void* d_ws, size_t ws_size,
                              hipStream_t stream) {
  const float* x  = (const float*)d_in[0];
  const float* gw = (const float*)d_in[1];
  const float* gb = (const float*)d_in[2];
  const float* ew = (const float*)d_in[3];
  const float* eb = (const float*)d_in[4];
  float* out = (float*)d_out;

  // workspace layout (~36.6 MB)
  char* ws = (char*)d_ws;
  unsigned short* WbT  = (unsigned short*)ws;                          // 1 MB
  unsigned short* xb   = (unsigned short*)(ws + 1048576);              // 33 MB (unsorted bf16 [NTOK][256])
  float2*         wpr  = (float2*)(ws + 34734080);                     // 512 KB
  float2*         wsr  = (float2*)(ws + 35258368);                     // sorted weights
  int*            tord = (int*)(ws + 35784704);                        // sorted token ids
  unsigned char*  pid  = (unsigned char*)(ws + 36047872);              // 64 KB
  int*            h2d  = (int*)(ws + 36113408);                        // 256 KB  [1024][64]
  int*            lb2d = (int*)(ws + 36375552);                        // 256 KB  [1024][64]
  int*            cnt  = (int*)(ws + 36637696);                        // 256 B
  int*            strt = (int*)(ws + 36637952);                        // 256 B
  int4*           meta = (int4*)(ws + 36638208);                       // 9.2 KB

  hipFuncSetAttribute((const void*)moe_gemm_pair, hipFuncAttributeMaxDynamicSharedMemorySize, 67072);

  gating<<<NGB, 512, 0, stream>>>(x, gw, gb, ew, WbT, xb, pid, wpr, h2d);
  scan1_k<<<64, NGB, 0, stream>>>(h2d, lb2d, cnt);
  scan2_k<<<1, 64, 0, stream>>>(cnt, strt, meta);
  route_k<<<NGB, 64, 0, stream>>>(pid, wpr, strt, lb2d, wsr, tord);
  moe_gemm_pair<<<2 * NMETA, 512, 67072, stream>>>(xb, WbT, eb, wsr, tord, meta, out);
}